// Round 11
// baseline (332.995 us; speedup 1.0000x reference)
//
#include <hip/hip_runtime.h>

#define INSZ   2048
#define NH1    256
#define NH2    64
#define NB     8
#define BATCH  16384

#define TS        16                 // rows per wave-tile (v14)
#define MAXTILES  (BATCH / TS)       // 1024
#define GRIDX     (NB * MAXTILES)    // 8192, bkt = blockIdx & 7 -> XCD pin

// W1f: [bkt][kb(64)][cb(16)][lane(64)][8] bf16
#define W1F_U4   (NB * 64 * 16 * 64)        // 524288 uint4
#define W2F_U4   (NB * 8 * 4 * 64)          // 16384 uint4

// ws layout (bytes)
#define META_OFF  0                  // 32 ints: cnt[8], off[8], cursor[8]
#define ORDER_OFF 1024               // 16384 ints
#define W1F_OFF   (1024 + BATCH * 4)            // 66560
#define W2F_OFF   (W1F_OFF + W1F_U4 * 16)       // 8,455,168
#define WS_NEED   (W2F_OFF + W2F_U4 * 16)       // 8,717,312

typedef float f4  __attribute__((ext_vector_type(4)));
typedef float f32x4 __attribute__((ext_vector_type(4)));
typedef short bf16x8 __attribute__((ext_vector_type(8)));

__device__ __forceinline__ unsigned short f2bf(float f) {
    unsigned u = __float_as_uint(f);
    u += 0x7fffu + ((u >> 16) & 1u);   // RNE
    return (unsigned short)(u >> 16);
}
__device__ __forceinline__ float clamp01(float v) { return fminf(fmaxf(v, 0.0f), 1.0f); }
__device__ __forceinline__ unsigned pack2(float a, float b) {
    return (unsigned)f2bf(a) | ((unsigned)f2bf(b) << 16);
}

// ============================ pre-pass kernels ============================

__global__ void k_countscan(const int* __restrict__ idx, int* __restrict__ meta) {
    __shared__ int scnt[NB];
    int t = threadIdx.x;
    if (t < NB) scnt[t] = 0;
    __syncthreads();
    int local[NB];
#pragma unroll
    for (int bb = 0; bb < NB; bb++) local[bb] = 0;
    for (int i = t; i < BATCH; i += 1024) {
        int b = idx[i];
#pragma unroll
        for (int bb = 0; bb < NB; bb++) local[bb] += (b == bb) ? 1 : 0;
    }
#pragma unroll
    for (int bb = 0; bb < NB; bb++) {
        int v = local[bb];
        v += __shfl_xor(v, 1);  v += __shfl_xor(v, 2);  v += __shfl_xor(v, 4);
        v += __shfl_xor(v, 8);  v += __shfl_xor(v, 16); v += __shfl_xor(v, 32);
        if ((t & 63) == 0) atomicAdd(&scnt[bb], v);
    }
    __syncthreads();
    if (t == 0) {
        int run = 0;
        for (int b = 0; b < NB; b++) {
            int c = scnt[b];
            meta[b]      = c;
            meta[8 + b]  = run;
            meta[16 + b] = run;   // scatter cursor
            run += c;
        }
    }
}

__global__ void k_scatter(const int* __restrict__ idx, int* __restrict__ meta,
                          int* __restrict__ order) {
    __shared__ int wcnt[16][NB];
    __shared__ int sbase[NB];
    int t = threadIdx.x;
    int i = blockIdx.x * 1024 + t;
    int b = idx[i];
    int wv = t >> 6, lane = t & 63;
    unsigned long long mymask = 0;
#pragma unroll
    for (int bb = 0; bb < NB; bb++) {
        unsigned long long m = __ballot(b == bb);
        if (b == bb) mymask = m;
        if (lane == bb) wcnt[wv][bb] = (int)__popcll(m);
    }
    int myrank = (int)__popcll(mymask & ((1ull << lane) - 1ull));
    __syncthreads();
    if (t < NB) {
        int sum = 0;
        for (int w2 = 0; w2 < 16; w2++) { int c = wcnt[w2][t]; wcnt[w2][t] = sum; sum += c; }
        sbase[t] = atomicAdd(&meta[16 + t], sum);
    }
    __syncthreads();
    order[sbase[b] + wcnt[wv][b] + myrank] = i;
}

// pack W1/W2 into per-lane MFMA B-fragment order (bf16), coalesced reads
__global__ void k_pack(const float* __restrict__ W1, const float* __restrict__ W2,
                       uint4* __restrict__ W1f, uint4* __restrict__ W2f) {
    int u = blockIdx.x * 256 + threadIdx.x;
    if (u < W1F_U4) {
        int k8 = u & 255, row = (u >> 8) & 255, bkt = u >> 16;
        int kb = k8 >> 2, quad = k8 & 3;
        int cb = row >> 4, l15 = row & 15;
        const float* p = W1 + ((size_t)(bkt * NH1 + row)) * INSZ + k8 * 8;
        f4 lo = *(const f4*)p, hi = *(const f4*)(p + 4);
        uint4 o;
        o.x = pack2(lo[0], lo[1]); o.y = pack2(lo[2], lo[3]);
        o.z = pack2(hi[0], hi[1]); o.w = pack2(hi[2], hi[3]);
        W1f[((bkt * 64 + kb) * 16 + cb) * 64 + quad * 16 + l15] = o;
    } else {
        int v = u - W1F_U4;
        if (v >= W2F_U4) return;
        int k8 = v & 31, row = (v >> 5) & 63, bkt = v >> 11;
        int kb2 = k8 >> 2, quad = k8 & 3;
        int cg2 = row >> 4, l15 = row & 15;
        const float* p = W2 + ((size_t)(bkt * NH2 + row)) * NH1 + k8 * 8;
        f4 lo = *(const f4*)p, hi = *(const f4*)(p + 4);
        uint4 o;
        o.x = pack2(lo[0], lo[1]); o.y = pack2(lo[2], lo[3]);
        o.z = pack2(hi[0], hi[1]); o.w = pack2(hi[2], hi[3]);
        W2f[((bkt * 8 + kb2) * 4 + cg2) * 64 + quad * 16 + l15] = o;
    }
}

// ============================ main fused kernel ============================
// v14: WAVE-AUTONOMOUS. Eight gang-synced structures (v6-v13) all land at
// 80-105us; arithmetic says 25-40 is available; the HBM flow of gang-synced
// kernels is bursty (740GB/s avg). The one measured latency-hiding mechanism
// on this chip is TLP between INDEPENDENT waves (m114) - never yet tried:
// all prior variants re-synchronized waves every step or slab, so latency
// holes recur in phase across the whole CU.
//   Here each wave owns a 16-row x 64-col tile end-to-end with NO barrier,
// NO LDS, NO cross-wave coupling in the K-loop: A-frags gathered straight
// from x (lane (l15,quad) -> row l15, k quad*8; 16x128B segments, L1-shared
// across the block's 4 waves which cover col-chunks of the same rows),
// 4 W-frags from L2-resident W1f, 4 MFMA, 64 steps. ~1024 active blocks =
// 4/CU = 16 independent waves/CU; waves drift out of phase -> continuous
// HBM flow. Layer 2/3 in-block: 8KB sh1 stage + 3 barriers total.

#define MFMA16 __builtin_amdgcn_mfma_f32_16x16x32_bf16

__global__ __launch_bounds__(256, 4) void fused_v14(
    const float* __restrict__ x, const int* __restrict__ meta,
    const int* __restrict__ order,
    const short* __restrict__ W1f, const short* __restrict__ W2f,
    const float* __restrict__ b1, const float* __restrict__ b2,
    const float* __restrict__ W3, const float* __restrict__ b3,
    float* __restrict__ out)
{
    const int bkt  = blockIdx.x & 7;
    const int tile = blockIdx.x >> 3;     // identity: actives dense at low blockIdx
    const int cnt  = meta[bkt];
    const int base = tile * TS;
    if (base >= cnt) return;
    const int off = meta[8 + bkt];

    __shared__ short sh1[TS * 264];      // 8.25 KB  h1 (bf16)
    __shared__ float sPart[4][TS];       // 256 B

    const int t = threadIdx.x;
    const int lane = t & 63, w = t >> 6;       // 4 waves, wave w = cols w*64..+63
    const int l15 = lane & 15, quad = lane >> 4;

    // per-lane x gather pointer: row = base+l15 (clamped), k-offset = quad*8
    int ir = base + l15; if (ir > cnt - 1) ir = cnt - 1;
    const float* xg = x + (size_t)order[off + ir] * INSZ + quad * 8;

    // W1 frags: wave w covers cb = 4w .. 4w+3
    const short* wp = W1f + ((size_t)bkt << 19) + (size_t)(4 * w) * 512 + lane * 8;

    f32x4 acc[4];
#pragma unroll
    for (int i = 0; i < 4; i++) acc[i] = (f32x4)0.0f;

    // ---- K-loop: fully wave-local, no sync, no LDS ----
#pragma unroll 2
    for (int kb = 0; kb < 64; kb++) {
        f4 lo = *(const f4*)(xg + kb * 32);
        f4 hi = *(const f4*)(xg + kb * 32 + 4);
        const short* wq = wp + (size_t)kb * 8192;
        bf16x8 w0 = *(const bf16x8*)(wq);
        bf16x8 w1 = *(const bf16x8*)(wq + 512);
        bf16x8 w2 = *(const bf16x8*)(wq + 1024);
        bf16x8 w3r = *(const bf16x8*)(wq + 1536);
        uint4 u;
        u.x = pack2(lo[0], lo[1]); u.y = pack2(lo[2], lo[3]);
        u.z = pack2(hi[0], hi[1]); u.w = pack2(hi[2], hi[3]);
        bf16x8 a = *(bf16x8*)&u;
        acc[0] = MFMA16(a, w0, acc[0], 0, 0, 0);
        acc[1] = MFMA16(a, w1, acc[1], 0, 0, 0);
        acc[2] = MFMA16(a, w2, acc[2], 0, 0, 0);
        acc[3] = MFMA16(a, w3r, acc[3], 0, 0, 0);
    }

    // ---- layer-1 epilogue: bias + clip01 -> sh1 (16 rows x 256 cols) ----
#pragma unroll
    for (int i = 0; i < 4; i++) {
        int col = w * 64 + i * 16 + l15;
        float bias = b1[bkt * NH1 + col];
#pragma unroll
        for (int r = 0; r < 4; r++) {
            int row = quad * 4 + r;          // C-layout: col=lane&15, row=quad*4+reg
            sh1[row * 264 + col] = (short)f2bf(clamp01(acc[i][r] + bias));
        }
    }
    __syncthreads();

    // ---- layer 2: wave w -> h2 cols w*16..+15, all 16 rows ----
    f32x4 c2 = (f32x4)0.0f;
    const short* w2p = W2f + (size_t)bkt * 16384 + lane * 8;
#pragma unroll
    for (int kb2 = 0; kb2 < 8; kb2++) {
        bf16x8 a2 = *(const bf16x8*)&sh1[l15 * 264 + kb2 * 32 + quad * 8];
        bf16x8 bw = *(const bf16x8*)(w2p + (kb2 * 4 + w) * 512);
        c2 = MFMA16(a2, bw, c2, 0, 0, 0);
    }

    // ---- layer-2 epilogue + layer-3 partial dot ----
    {
        int n2 = w * 16 + l15;
        float bias2 = b2[bkt * NH2 + n2];
        float w3v   = W3[bkt * NH2 + n2];
#pragma unroll
        for (int r = 0; r < 4; r++) {
            float pp = clamp01(c2[r] + bias2) * w3v;
            pp += __shfl_xor(pp, 1); pp += __shfl_xor(pp, 2);
            pp += __shfl_xor(pp, 4); pp += __shfl_xor(pp, 8);
            if (l15 == 0) sPart[w][quad * 4 + r] = pp;
        }
    }
    __syncthreads();
    if (t < TS && base + t < cnt)
        out[order[off + base + t]] =
            sPart[0][t] + sPart[1][t] + sPart[2][t] + sPart[3][t] + b3[bkt];
}

// ============================ naive fallback ============================

__global__ void naive_mlp(const float* __restrict__ x, const int* __restrict__ idx,
                          const float* __restrict__ W1, const float* __restrict__ b1,
                          const float* __restrict__ W2, const float* __restrict__ b2,
                          const float* __restrict__ W3, const float* __restrict__ b3,
                          float* __restrict__ out)
{
    int i = blockIdx.x;
    int b = idx[i];
    __shared__ float sx[INSZ];
    __shared__ float sh1n[NH1];
    __shared__ float sh2n[NH2];
    for (int t = threadIdx.x; t < INSZ; t += 256) sx[t] = x[(size_t)i * INSZ + t];
    __syncthreads();
    int j = threadIdx.x;
    {
        const float* wr = W1 + (size_t)(b * NH1 + j) * INSZ;
        float acc = b1[b * NH1 + j];
        for (int k = 0; k < INSZ; k++) acc += sx[k] * wr[k];
        sh1n[j] = fminf(fmaxf(acc, 0.f), 1.f);
    }
    __syncthreads();
    if (j < NH2) {
        const float* wr = W2 + (size_t)(b * NH2 + j) * NH1;
        float acc = b2[b * NH2 + j];
        for (int k = 0; k < NH1; k++) acc += sh1n[k] * wr[k];
        sh2n[j] = fminf(fmaxf(acc, 0.f), 1.f);
    }
    __syncthreads();
    if (j == 0) {
        float acc = b3[b];
        for (int k = 0; k < NH2; k++) acc += sh2n[k] * W3[b * NH2 + k];
        out[i] = acc;
    }
}

extern "C" void kernel_launch(void* const* d_in, const int* in_sizes, int n_in,
                              void* d_out, int out_size, void* d_ws, size_t ws_size,
                              hipStream_t stream) {
    const float* x  = (const float*)d_in[0];
    const int* bidx = (const int*)d_in[1];
    const float* W1 = (const float*)d_in[2];
    const float* b1 = (const float*)d_in[3];
    const float* W2 = (const float*)d_in[4];
    const float* b2 = (const float*)d_in[5];
    const float* W3 = (const float*)d_in[6];
    const float* b3 = (const float*)d_in[7];
    float* out = (float*)d_out;

    if (ws_size >= (size_t)WS_NEED) {
        char* ws = (char*)d_ws;
        int*   meta  = (int*)(ws + META_OFF);
        int*   order = (int*)(ws + ORDER_OFF);
        uint4* W1f   = (uint4*)(ws + W1F_OFF);
        uint4* W2f   = (uint4*)(ws + W2F_OFF);

        k_countscan<<<1, 1024, 0, stream>>>(bidx, meta);
        k_scatter<<<BATCH / 1024, 1024, 0, stream>>>(bidx, meta, order);
        k_pack<<<(W1F_U4 + W2F_U4) / 256, 256, 0, stream>>>(W1, W2, W1f, W2f);
        fused_v14<<<GRIDX, 256, 0, stream>>>(x, meta, order,
                                             (const short*)W1f, (const short*)W2f,
                                             b1, b2, W3, b3, out);
    } else {
        naive_mlp<<<BATCH, 256, 0, stream>>>(x, bidx, W1, b1, W2, b2, W3, b3, out);
    }
}

// Round 12
// 275.934 us; speedup vs baseline: 1.2068x; 1.2068x over previous
//
#include <hip/hip_runtime.h>

#define INSZ   2048
#define NH1    256
#define NH2    64
#define NB     8
#define BATCH  16384

#define TS        64                 // rows per block-tile
#define MAXTILES  (BATCH / TS)       // 256
#define GRIDX     (NB * MAXTILES)    // 2048, bkt = blockIdx & 7 -> XCD pin

// W1f: [bkt][kb(64)][cb(16)][lane(64)][8] bf16
#define W1F_U4   (NB * 64 * 16 * 64)        // 524288 uint4
#define W2F_U4   (NB * 8 * 4 * 64)          // 16384 uint4

// ws layout (bytes)
#define META_OFF  0
#define ORDER_OFF 1024
#define W1F_OFF   (1024 + BATCH * 4)
#define W2F_OFF   (W1F_OFF + W1F_U4 * 16)
#define WS_NEED   (W2F_OFF + W2F_U4 * 16)

typedef float f4  __attribute__((ext_vector_type(4)));
typedef float f32x4 __attribute__((ext_vector_type(4)));
typedef short bf16x8 __attribute__((ext_vector_type(8)));

__device__ __forceinline__ unsigned short f2bf(float f) {
    unsigned u = __float_as_uint(f);
    u += 0x7fffu + ((u >> 16) & 1u);   // RNE
    return (unsigned short)(u >> 16);
}
__device__ __forceinline__ float clamp01(float v) { return fminf(fmaxf(v, 0.0f), 1.0f); }
__device__ __forceinline__ unsigned pack2(float a, float b) {
    return (unsigned)f2bf(a) | ((unsigned)f2bf(b) << 16);
}

// ============================ pre-pass kernels ============================

__global__ void k_countscan(const int* __restrict__ idx, int* __restrict__ meta) {
    __shared__ int scnt[NB];
    int t = threadIdx.x;
    if (t < NB) scnt[t] = 0;
    __syncthreads();
    int local[NB];
#pragma unroll
    for (int bb = 0; bb < NB; bb++) local[bb] = 0;
    for (int i = t; i < BATCH; i += 1024) {
        int b = idx[i];
#pragma unroll
        for (int bb = 0; bb < NB; bb++) local[bb] += (b == bb) ? 1 : 0;
    }
#pragma unroll
    for (int bb = 0; bb < NB; bb++) {
        int v = local[bb];
        v += __shfl_xor(v, 1);  v += __shfl_xor(v, 2);  v += __shfl_xor(v, 4);
        v += __shfl_xor(v, 8);  v += __shfl_xor(v, 16); v += __shfl_xor(v, 32);
        if ((t & 63) == 0) atomicAdd(&scnt[bb], v);
    }
    __syncthreads();
    if (t == 0) {
        int run = 0;
        for (int b = 0; b < NB; b++) {
            int c = scnt[b];
            meta[b]      = c;
            meta[8 + b]  = run;
            meta[16 + b] = run;
            run += c;
        }
    }
}

__global__ void k_scatter(const int* __restrict__ idx, int* __restrict__ meta,
                          int* __restrict__ order) {
    __shared__ int wcnt[16][NB];
    __shared__ int sbase[NB];
    int t = threadIdx.x;
    int i = blockIdx.x * 1024 + t;
    int b = idx[i];
    int wv = t >> 6, lane = t & 63;
    unsigned long long mymask = 0;
#pragma unroll
    for (int bb = 0; bb < NB; bb++) {
        unsigned long long m = __ballot(b == bb);
        if (b == bb) mymask = m;
        if (lane == bb) wcnt[wv][bb] = (int)__popcll(m);
    }
    int myrank = (int)__popcll(mymask & ((1ull << lane) - 1ull));
    __syncthreads();
    if (t < NB) {
        int sum = 0;
        for (int w2 = 0; w2 < 16; w2++) { int c = wcnt[w2][t]; wcnt[w2][t] = sum; sum += c; }
        sbase[t] = atomicAdd(&meta[16 + t], sum);
    }
    __syncthreads();
    order[sbase[b] + wcnt[wv][b] + myrank] = i;
}

// pack W1/W2 into per-lane MFMA B-fragment order (bf16), coalesced reads
__global__ void k_pack(const float* __restrict__ W1, const float* __restrict__ W2,
                       uint4* __restrict__ W1f, uint4* __restrict__ W2f) {
    int u = blockIdx.x * 256 + threadIdx.x;
    if (u < W1F_U4) {
        int k8 = u & 255, row = (u >> 8) & 255, bkt = u >> 16;
        int kb = k8 >> 2, quad = k8 & 3;
        int cb = row >> 4, l15 = row & 15;
        const float* p = W1 + ((size_t)(bkt * NH1 + row)) * INSZ + k8 * 8;
        f4 lo = *(const f4*)p, hi = *(const f4*)(p + 4);
        uint4 o;
        o.x = pack2(lo[0], lo[1]); o.y = pack2(lo[2], lo[3]);
        o.z = pack2(hi[0], hi[1]); o.w = pack2(hi[2], hi[3]);
        W1f[((bkt * 64 + kb) * 16 + cb) * 64 + quad * 16 + l15] = o;
    } else {
        int v = u - W1F_U4;
        if (v >= W2F_U4) return;
        int k8 = v & 31, row = (v >> 5) & 63, bkt = v >> 11;
        int kb2 = k8 >> 2, quad = k8 & 3;
        int cg2 = row >> 4, l15 = row & 15;
        const float* p = W2 + ((size_t)(bkt * NH2 + row)) * NH1 + k8 * 8;
        f4 lo = *(const f4*)p, hi = *(const f4*)(p + 4);
        uint4 o;
        o.x = pack2(lo[0], lo[1]); o.y = pack2(lo[2], lo[3]);
        o.z = pack2(hi[0], hi[1]); o.w = pack2(hi[2], hi[3]);
        W2f[((bkt * 8 + kb2) * 4 + cg2) * 64 + quad * 16 + l15] = o;
    }
}

// ============================ main fused kernel ============================
// v15: full asm-controlled K-loop. Root cause of the ~3000cy/step invariant
// (v6-v14): hipcc allocates minimal VGPRs (36-64 measured) and serializes
// every vm load behind a wait (per-step time ~= Nloads x latency; v14: 6
// loads x ~950cy = 5760cy/step exactly matches 153us/64). v12's asm W-loads
// didn't escape because the compiler sees glds's LDS write and drains vmcnt
// before its OWN ds_reads. v15 closes that hole: A-frag ds_reads are inline
// asm too (+ lgkmcnt(0) + sched_barrier, rule #18) -> no compiler-visible
// LDS access in the loop, all waits hand-counted:
//   per step k: [vmcnt(6) retires W(k)x4,G(k); ages: W=2, G=3 steps]
//   -> s_barrier (all waves' G(k) now LDS-visible; reads of buf k finish
//      before barrier k+1, G(k+4) issued after it -> RAW+WAR safe)
//   -> 4x asm ds_read_b128 (XOR-swizzled) -> lgkm(0) -> cvt -> 8 MFMA
//   -> issue W(k+2)x4 (asm dwordx4, into the set just consumed)
//   -> issue glds G(k+3). Steady in-flight = 11; tail waits 6/6/5/0.
// Traffic: x 134MB (HBM/L3) + W 256MB (L2, bkt XCD-pinned) = 390MB/dispatch.

#define MFMA16 __builtin_amdgcn_mfma_f32_16x16x32_bf16
#define WLD(D, P) asm volatile("global_load_dwordx4 %0, %1, off" : "=&v"(D) : "v"(P))
#define DSR(D, A, IMM) asm volatile("ds_read_b128 %0, %1 offset:" #IMM : "=&v"(D) : "v"(A))
#define GLDS16(SRC, DST) __builtin_amdgcn_global_load_lds( \
    (const __attribute__((address_space(1))) unsigned int*)(SRC), \
    (__attribute__((address_space(3))) unsigned int*)(DST), 16, 0, 0)

__global__ __launch_bounds__(512, 2) void fused_v15(
    const float* __restrict__ x, const int* __restrict__ meta,
    const int* __restrict__ order,
    const short* __restrict__ W1f, const short* __restrict__ W2f,
    const float* __restrict__ b1, const float* __restrict__ b2,
    const float* __restrict__ W3, const float* __restrict__ b3,
    float* __restrict__ out)
{
    const int bkt  = blockIdx.x & 7;
    const int tile = blockIdx.x >> 3;     // identity: 1 active block per CU
    const int cnt  = meta[bkt];
    const int base = tile * TS;
    if (base >= cnt) return;
    const int off = meta[8 + bkt];

    __shared__ float sXf[4][2048];       // 32 KB: 4 x-step bufs (fp32, swizzled)
    __shared__ short sh1[TS * 264];      // 33.8 KB
    __shared__ float sPart[2][TS];

    const int t = threadIdx.x;
    const int lane = t & 63, w = t >> 6;
    const int l15 = lane & 15, quad = lane >> 4;
    const int g = w & 1, c4 = w >> 1;     // row-group (32), col-group (64)

    // ---- x staging: wave w stages rows w*8..+7; XOR chunk involution ----
    const int srow = lane >> 3, sj = (lane & 7) ^ srow;
    int sir = base + w * 8 + srow; if (sir > cnt - 1) sir = cnt - 1;
    const float* xsl = x + (size_t)order[off + sir] * INSZ + sj * 4;
    float* ldst = &sXf[0][0] + w * 256;   // + buf*2048 per use (wave-uniform)

    // ---- A-frag LDS byte addresses (loop-invariant; offset imm = buf*8192) ----
    const unsigned ldsb =
        (unsigned)(size_t)(__attribute__((address_space(3))) char*)&sXf[0][0];
    const int rho = l15 & 7;
    const int grp0 = (g * 32 + l15) >> 3, grp1 = (g * 32 + 16 + l15) >> 3;
    const int cl = (((2 * quad) ^ rho) << 4), ch = (((2 * quad + 1) ^ rho) << 4);
    const unsigned aA0L = ldsb + grp0 * 1024 + rho * 128 + cl;
    const unsigned aA0H = ldsb + grp0 * 1024 + rho * 128 + ch;
    const unsigned aA1L = ldsb + grp1 * 1024 + rho * 128 + cl;
    const unsigned aA1H = ldsb + grp1 * 1024 + rho * 128 + ch;

    // per-wave W1 fragment base: frag (kb, cb=c4*4+i) at kb*8192 + i*512 (+lane*8)
    const short* wp = W1f + ((size_t)bkt << 19) + (size_t)(c4 * 4) * 512 + lane * 8;

    // ---- preload + pin epilogue scalars ----
    const int rw = w & 3, ch2 = w >> 2;
    float b1v0 = b1[bkt * NH1 + c4 * 64 + 0 * 16 + l15];
    float b1v1 = b1[bkt * NH1 + c4 * 64 + 1 * 16 + l15];
    float b1v2 = b1[bkt * NH1 + c4 * 64 + 2 * 16 + l15];
    float b1v3 = b1[bkt * NH1 + c4 * 64 + 3 * 16 + l15];
    float b2v0 = b2[bkt * NH2 + (ch2 * 2 + 0) * 16 + l15];
    float b2v1 = b2[bkt * NH2 + (ch2 * 2 + 1) * 16 + l15];
    float w3v0 = W3[bkt * NH2 + (ch2 * 2 + 0) * 16 + l15];
    float w3v1 = W3[bkt * NH2 + (ch2 * 2 + 1) * 16 + l15];
    float b3v  = b3[bkt];
    asm volatile("" :: "v"(b1v0), "v"(b1v1), "v"(b1v2), "v"(b1v3),
                       "v"(b2v0), "v"(b2v1), "v"(w3v0), "v"(w3v1), "v"(b3v));

    f32x4 acc[2][4];
#pragma unroll
    for (int a = 0; a < 2; a++)
#pragma unroll
        for (int i = 0; i < 4; i++) acc[a][i] = (f32x4)0.0f;

    bf16x8 wa0, wa1, wa2, wa3, wb0, wb1, wb2, wb3;   // W sets: A=even kb, B=odd

    // ---- prologue issue order (counts depend on it): W0x4, G0, W1x4, G1, G2 ----
    WLD(wa0, wp);            WLD(wa1, wp + 512);
    WLD(wa2, wp + 1024);     WLD(wa3, wp + 1536);
    GLDS16(xsl, ldst);
    {
        const short* wq = wp + 8192;
        WLD(wb0, wq);        WLD(wb1, wq + 512);
        WLD(wb2, wq + 1024); WLD(wb3, wq + 1536);
    }
    GLDS16(xsl + 32, ldst + 2048);
    GLDS16(xsl + 64, ldst + 4096);
    __builtin_amdgcn_sched_barrier(0);
    // step 0's vmcnt(6) retires W0x4+G0; no separate prologue wait needed.

    // Step body. In-flight at wait (steady): W(k)x4,G(k),G(k+1),W(k+1)x4,G(k+2)=11.
#define L1_STEP(KB, BUFI, GBUFI, W0, W1, W2, W3r, DOW, DOG, VMN)                        \
    {                                                                                   \
        asm volatile("s_waitcnt vmcnt(" #VMN ")");                                      \
        __builtin_amdgcn_s_barrier();                                                   \
        __builtin_amdgcn_sched_barrier(0);                                              \
        f4 l0, h0, l1, h1;                                                              \
        DSR(l0, aA0L, BUFI);  DSR(h0, aA0H, BUFI);                                      \
        DSR(l1, aA1L, BUFI);  DSR(h1, aA1H, BUFI);                                      \
        asm volatile("s_waitcnt lgkmcnt(0)");                                           \
        __builtin_amdgcn_sched_barrier(0);                                              \
        bf16x8 a0, a1;                                                                  \
        { uint4 u; u.x = pack2(l0[0], l0[1]); u.y = pack2(l0[2], l0[3]);                \
          u.z = pack2(h0[0], h0[1]); u.w = pack2(h0[2], h0[3]); a0 = *(bf16x8*)&u; }    \
        { uint4 u; u.x = pack2(l1[0], l1[1]); u.y = pack2(l1[2], l1[3]);                \
          u.z = pack2(h1[0], h1[1]); u.w = pack2(h1[2], h1[3]); a1 = *(bf16x8*)&u; }    \
        acc[0][0] = MFMA16(a0, W0, acc[0][0], 0, 0, 0);                                 \
        acc[0][1] = MFMA16(a0, W1, acc[0][1], 0, 0, 0);                                 \
        acc[0][2] = MFMA16(a0, W2, acc[0][2], 0, 0, 0);                                 \
        acc[0][3] = MFMA16(a0, W3r, acc[0][3], 0, 0, 0);                                \
        acc[1][0] = MFMA16(a1, W0, acc[1][0], 0, 0, 0);                                 \
        acc[1][1] = MFMA16(a1, W1, acc[1][1], 0, 0, 0);                                 \
        acc[1][2] = MFMA16(a1, W2, acc[1][2], 0, 0, 0);                                 \
        acc[1][3] = MFMA16(a1, W3r, acc[1][3], 0, 0, 0);                                \
        if (DOW) {                                                                      \
            const short* wq = wp + (size_t)((KB) + 2) * 8192;                           \
            WLD(W0, wq);        WLD(W1, wq + 512);                                      \
            WLD(W2, wq + 1024); WLD(W3r, wq + 1536);                                    \
        }                                                                               \
        __builtin_amdgcn_sched_barrier(0);                                              \
        if (DOG) GLDS16(xsl + (size_t)((KB) + 3) * 32, ldst + (GBUFI) * 2048);          \
        __builtin_amdgcn_sched_barrier(0);                                              \
    }

#pragma unroll 1
    for (int kb = 0; kb < 60; kb += 4) {
        L1_STEP(kb + 0, 0,     3, wa0, wa1, wa2, wa3, 1, 1, 6)
        L1_STEP(kb + 1, 8192,  0, wb0, wb1, wb2, wb3, 1, 1, 6)
        L1_STEP(kb + 2, 16384, 1, wa0, wa1, wa2, wa3, 1, 1, 6)
        L1_STEP(kb + 3, 24576, 2, wb0, wb1, wb2, wb3, 1, 1, 6)
    }
    // tail: 60 (W62,G63), 61 (W63), 62, 63 — waits 6/6/5/0 (hand-simulated)
    L1_STEP(60, 0,     3, wa0, wa1, wa2, wa3, 1, 1, 6)
    L1_STEP(61, 8192,  0, wb0, wb1, wb2, wb3, 1, 0, 6)
    L1_STEP(62, 16384, 0, wa0, wa1, wa2, wa3, 0, 0, 5)
    L1_STEP(63, 24576, 0, wb0, wb1, wb2, wb3, 0, 0, 0)
#undef L1_STEP

    // ---- layer-1 epilogue: bias + clip01 -> sh1 (64 x 256) ----
    {
        float b1v[4] = {b1v0, b1v1, b1v2, b1v3};
#pragma unroll
        for (int i = 0; i < 4; i++) {
            int col = c4 * 64 + i * 16 + l15;
#pragma unroll
            for (int a = 0; a < 2; a++)
#pragma unroll
                for (int r = 0; r < 4; r++) {
                    int row = g * 32 + a * 16 + quad * 4 + r;
                    sh1[row * 264 + col] = (short)f2bf(clamp01(acc[a][i][r] + b1v[i]));
                }
        }
    }
    __syncthreads();

    // ---- layer 2: wave w -> h2 rows (w&3)*16..+15, cols (w>>2)*32..+31 ----
    f32x4 c2[2];
    c2[0] = (f32x4)0.0f; c2[1] = (f32x4)0.0f;
    const short* w2p = W2f + (size_t)bkt * 16384 + lane * 8;
#pragma unroll
    for (int kb2 = 0; kb2 < 8; kb2++) {
        bf16x8 a2 = *(const bf16x8*)&sh1[(rw * 16 + l15) * 264 + kb2 * 32 + quad * 8];
#pragma unroll
        for (int j = 0; j < 2; j++) {
            bf16x8 bw = *(const bf16x8*)(w2p + (kb2 * 4 + ch2 * 2 + j) * 512);
            c2[j] = MFMA16(a2, bw, c2[j], 0, 0, 0);
        }
    }

    // ---- layer-2 epilogue + layer-3 partial dot ----
    float s[4] = {0, 0, 0, 0};
#pragma unroll
    for (int r = 0; r < 4; r++) {
        s[r] += clamp01(c2[0][r] + b2v0) * w3v0;
        s[r] += clamp01(c2[1][r] + b2v1) * w3v1;
    }
#pragma unroll
    for (int r = 0; r < 4; r++) {
        float pp = s[r];
        pp += __shfl_xor(pp, 1); pp += __shfl_xor(pp, 2);
        pp += __shfl_xor(pp, 4); pp += __shfl_xor(pp, 8);
        if (l15 == 0) sPart[ch2][rw * 16 + quad * 4 + r] = pp;
    }
    __syncthreads();
    if (t < TS && base + t < cnt)
        out[order[off + base + t]] = sPart[0][t] + sPart[1][t] + b3v;
}

// ============================ naive fallback ============================

__global__ void naive_mlp(const float* __restrict__ x, const int* __restrict__ idx,
                          const float* __restrict__ W1, const float* __restrict__ b1,
                          const float* __restrict__ W2, const float* __restrict__ b2,
                          const float* __restrict__ W3, const float* __restrict__ b3,
                          float* __restrict__ out)
{
    int i = blockIdx.x;
    int b = idx[i];
    __shared__ float sx[INSZ];
    __shared__ float sh1n[NH1];
    __shared__ float sh2n[NH2];
    for (int t = threadIdx.x; t < INSZ; t += 256) sx[t] = x[(size_t)i * INSZ + t];
    __syncthreads();
    int j = threadIdx.x;
    {
        const float* wr = W1 + (size_t)(b * NH1 + j) * INSZ;
        float acc = b1[b * NH1 + j];
        for (int k = 0; k < INSZ; k++) acc += sx[k] * wr[k];
        sh1n[j] = fminf(fmaxf(acc, 0.f), 1.f);
    }
    __syncthreads();
    if (j < NH2) {
        const float* wr = W2 + (size_t)(b * NH2 + j) * NH1;
        float acc = b2[b * NH2 + j];
        for (int k = 0; k < NH1; k++) acc += sh1n[k] * wr[k];
        sh2n[j] = fminf(fmaxf(acc, 0.f), 1.f);
    }
    __syncthreads();
    if (j == 0) {
        float acc = b3[b];
        for (int k = 0; k < NH2; k++) acc += sh2n[k] * W3[b * NH2 + k];
        out[i] = acc;
    }
}

extern "C" void kernel_launch(void* const* d_in, const int* in_sizes, int n_in,
                              void* d_out, int out_size, void* d_ws, size_t ws_size,
                              hipStream_t stream) {
    const float* x  = (const float*)d_in[0];
    const int* bidx = (const int*)d_in[1];
    const float* W1 = (const float*)d_in[2];
    const float* b1 = (const float*)d_in[3];
    const float* W2 = (const float*)d_in[4];
    const float* b2 = (const float*)d_in[5];
    const float* W3 = (const float*)d_in[6];
    const float* b3 = (const float*)d_in[7];
    float* out = (float*)d_out;

    if (ws_size >= (size_t)WS_NEED) {
        char* ws = (char*)d_ws;
        int*   meta  = (int*)(ws + META_OFF);
        int*   order = (int*)(ws + ORDER_OFF);
        uint4* W1f   = (uint4*)(ws + W1F_OFF);
        uint4* W2f   = (uint4*)(ws + W2F_OFF);

        k_countscan<<<1, 1024, 0, stream>>>(bidx, meta);
        k_scatter<<<BATCH / 1024, 1024, 0, stream>>>(bidx, meta, order);
        k_pack<<<(W1F_U4 + W2F_U4) / 256, 256, 0, stream>>>(W1, W2, W1f, W2f);
        fused_v15<<<GRIDX, 512, 0, stream>>>(x, meta, order,
                                             (const short*)W1f, (const short*)W2f,
                                             b1, b2, W3, b3, out);
    } else {
        naive_mlp<<<BATCH, 256, 0, stream>>>(x, bidx, W1, b1, W2, b2, W3, b3, out);
    }
}